// Round 4
// baseline (229.228 us; speedup 1.0000x reference)
//
#include <hip/hip_runtime.h>
#include <math.h>

#define NHEAD 4
#define DHEAD 32
#define NPIX  4096
#define CIN   128
#define RP    4   // query row-tiles per wave (64 queries)

typedef __bf16 bf16_t;
typedef __bf16 bf16x8 __attribute__((ext_vector_type(8)));
typedef __bf16 bf16x4 __attribute__((ext_vector_type(4)));
typedef float  f32x4  __attribute__((ext_vector_type(4)));

// 1/sqrt(32) * log2(e): folded into q weights so softmax exp is bare exp2.
constexpr float QSCALE = 0.17677669529663687f * 1.4426950408889634f;

// ---------------------------------------------------------------------------
// QKV projection.  r14: prep_swz folded in — each wave loads its weight
// fragments as raw f32 (L2-hot, 192 KB total) and converts in-register.
// Removes one serialized dispatch from the pipeline.  Grid (512,2) as r13.
// ---------------------------------------------------------------------------
__global__ void __launch_bounds__(256) qkv_mfma(
    const float* __restrict__ x, const float* __restrict__ wqkv,
    ushort* __restrict__ qb, ushort* __restrict__ kb, ushort* __restrict__ vT) {
  __shared__ ushort Xls[32 * 136];
  const int blk = blockIdx.x, tid = threadIdx.x;
  const int half = blockIdx.y;
  const int wave = tid >> 6, lane = tid & 63;
  const int n = lane & 15, quad = lane >> 4;
  const int bb = blk >> 7;             // batch
  const int p0 = (blk & 127) * 32;     // 32-px tile

  {  // stage x[bb][c][p0..p0+31] -> Xls[p][c] bf16 (4x4 transpose)
    const int pc = tid & 7, c0 = (tid >> 3) * 4;
    const float* xp = x + ((size_t)bb * CIN + c0) * NPIX + p0 + pc * 4;
    float4 r0 = *(const float4*)xp;
    float4 r1 = *(const float4*)(xp + NPIX);
    float4 r2 = *(const float4*)(xp + 2 * NPIX);
    float4 r3 = *(const float4*)(xp + 3 * NPIX);
    bf16x4 w0 = {(bf16_t)r0.x, (bf16_t)r1.x, (bf16_t)r2.x, (bf16_t)r3.x};
    bf16x4 w1 = {(bf16_t)r0.y, (bf16_t)r1.y, (bf16_t)r2.y, (bf16_t)r3.y};
    bf16x4 w2 = {(bf16_t)r0.z, (bf16_t)r1.z, (bf16_t)r2.z, (bf16_t)r3.z};
    bf16x4 w3 = {(bf16_t)r0.w, (bf16_t)r1.w, (bf16_t)r2.w, (bf16_t)r3.w};
    *(bf16x4*)&Xls[(pc * 4 + 0) * 136 + c0] = w0;
    *(bf16x4*)&Xls[(pc * 4 + 1) * 136 + c0] = w1;
    *(bf16x4*)&Xls[(pc * 4 + 2) * 136 + c0] = w2;
    *(bf16x4*)&Xls[(pc * 4 + 3) * 136 + c0] = w3;
  }
  __syncthreads();

  bf16x8 xf[2][4];                     // [px-tile nt][k]
#pragma unroll
  for (int nt = 0; nt < 2; ++nt)
#pragma unroll
    for (int k = 0; k < 4; ++k)
      xf[nt][k] = *(const bf16x8*)&Xls[(nt * 16 + n) * 136 + k * 32 + quad * 8];

#pragma unroll
  for (int mt = 0; mt < 3; ++mt) {     // wave covers 48 oc = 3 tiles
    const int ot = half * 12 + wave * 3 + mt;   // 0..23
    const int type = ot >> 3;          // 0=q 1=k 2=v
    const int wt = ot & 7, head = wt >> 1, d0 = (wt & 1) * 16;
    const int bh = bb * NHEAD + head;
    const float sc = (type == 0) ? QSCALE : 1.f;
    bf16x8 wf4[4];
#pragma unroll
    for (int k = 0; k < 4; ++k) {
      const float* ws = wqkv + (size_t)(ot * 16 + n) * CIN + k * 32 + quad * 8;
      float4 a = *(const float4*)ws;
      float4 b = *(const float4*)(ws + 4);
      wf4[k] = (bf16x8){(bf16_t)(a.x * sc), (bf16_t)(a.y * sc),
                        (bf16_t)(a.z * sc), (bf16_t)(a.w * sc),
                        (bf16_t)(b.x * sc), (bf16_t)(b.y * sc),
                        (bf16_t)(b.z * sc), (bf16_t)(b.w * sc)};
    }
    f32x4 acc[2] = {{0.f, 0.f, 0.f, 0.f}, {0.f, 0.f, 0.f, 0.f}};
    if (type < 2) {
#pragma unroll
      for (int k = 0; k < 4; ++k)
#pragma unroll
        for (int nt = 0; nt < 2; ++nt)
          acc[nt] = __builtin_amdgcn_mfma_f32_16x16x32_bf16(wf4[k], xf[nt][k], acc[nt], 0, 0, 0);
      ushort* dst = (type == 0) ? qb : kb;
#pragma unroll
      for (int nt = 0; nt < 2; ++nt) {  // C[m=oc][n=px] -> [p][d] b64
        bf16x4 o = {(bf16_t)acc[nt][0], (bf16_t)acc[nt][1],
                    (bf16_t)acc[nt][2], (bf16_t)acc[nt][3]};
        *(bf16x4*)(dst + ((size_t)bh * NPIX + p0 + nt * 16 + n) * DHEAD + d0 + quad * 4) = o;
      }
    } else {
#pragma unroll
      for (int k = 0; k < 4; ++k)
#pragma unroll
        for (int nt = 0; nt < 2; ++nt)
          acc[nt] = __builtin_amdgcn_mfma_f32_16x16x32_bf16(xf[nt][k], wf4[k], acc[nt], 0, 0, 0);
#pragma unroll
      for (int nt = 0; nt < 2; ++nt) {  // C[m=px][n=d] -> vT[d][p] b64
        bf16x4 o = {(bf16_t)acc[nt][0], (bf16_t)acc[nt][1],
                    (bf16_t)acc[nt][2], (bf16_t)acc[nt][3]};
        *(bf16x4*)(vT + ((size_t)bh * DHEAD + d0 + n) * NPIX + p0 + nt * 16 + quad * 4) = o;
      }
    }
  }
}

// ---------------------------------------------------------------------------
// Flash attention.  r14: RP=4 (64 q/wave), 1024 blocks = 4 blocks/CU =
// 4 waves/SIMD (r1's occupancy, which regressed WITHOUT the XCD swizzle —
// its doubled K/V stream paid L3 latency and its prefetch window was halved).
// Now: swizzle keeps K/V L2-resident (r2: FETCH 34.9->12.4 MB), setprio
// kept, and the full 64-key double-buffered prefetch window is restored.
// ---------------------------------------------------------------------------
__device__ __forceinline__ void ft_load(const ushort* kb0, const ushort* vb0,
                                        int t, bf16x8* kf, bf16x8* vf) {
#pragma unroll
  for (int p = 0; p < 2; ++p) {
#pragma unroll
    for (int s = 0; s < 2; ++s)
      kf[p * 2 + s] = *(const bf16x8*)(kb0 + (size_t)(t * 64 + p * 32 + s * 4) * DHEAD);
#pragma unroll
    for (int dp = 0; dp < 2; ++dp)
      vf[p * 2 + dp] = *(const bf16x8*)(vb0 + (size_t)dp * 16 * NPIX + t * 64 + p * 32);
  }
}

__device__ __forceinline__ void ft_compute(const bf16x8* qf, const bf16x8* kf,
                                           const bf16x8* vf, const bf16x8 ones,
                                           f32x4 O[RP][2], f32x4* Ol) {
  const f32x4 zero = {0.f, 0.f, 0.f, 0.f};
  __builtin_amdgcn_s_setprio(1);
#pragma unroll
  for (int p = 0; p < 2; ++p) {
#pragma unroll
    for (int rp = 0; rp < RP; ++rp) {
      f32x4 sa = __builtin_amdgcn_mfma_f32_16x16x32_bf16(kf[p * 2 + 0], qf[rp], zero, 0, 0, 0);
      f32x4 sb = __builtin_amdgcn_mfma_f32_16x16x32_bf16(kf[p * 2 + 1], qf[rp], zero, 0, 0, 0);
      bf16x8 pf;
#pragma unroll
      for (int r = 0; r < 4; ++r) {
        pf[r]     = (bf16_t)__builtin_amdgcn_exp2f(sa[r]);
        pf[r + 4] = (bf16_t)__builtin_amdgcn_exp2f(sb[r]);
      }
      O[rp][0] = __builtin_amdgcn_mfma_f32_16x16x32_bf16(pf, vf[p * 2 + 0], O[rp][0], 0, 0, 0);
      O[rp][1] = __builtin_amdgcn_mfma_f32_16x16x32_bf16(pf, vf[p * 2 + 1], O[rp][1], 0, 0, 0);
      Ol[rp]   = __builtin_amdgcn_mfma_f32_16x16x32_bf16(pf, ones, Ol[rp], 0, 0, 0);
    }
  }
  __builtin_amdgcn_s_setprio(0);
}

__global__ void __launch_bounds__(256, 4) flash_mfma(
    const ushort* __restrict__ qb, const ushort* __restrict__ kbuf,
    const ushort* __restrict__ vTb, float* __restrict__ part) {
  const int tid = threadIdx.x, wave = tid >> 6, lane = tid & 63;
  const int n = lane & 15, quad = lane >> 4;

  // XCD swizzle: group g = (js,bh); its 16 q-blocks all share id%8.
  // id = (g>>3)<<7 | qbk<<3 | (g&7) — bijective over 1024.
  const int id = blockIdx.x;
  const int g  = (id & 7) | ((id >> 7) << 3);   // 0..63
  const int qbk = (id >> 3) & 15;               // 0..15
  const int bh = g >> 2;                        // 0..15
  const int js = g & 3;                         // 0..3
  const int qrel = qbk * 256 + wave * 64;

  const ushort* kg = kbuf + (size_t)bh * NPIX * DHEAD;
  const ushort* vg = vTb + (size_t)bh * DHEAD * NPIX;

  bf16x8 qf[RP];
#pragma unroll
  for (int rp = 0; rp < RP; ++rp)
    qf[rp] = *(const bf16x8*)(qb +
        ((size_t)bh * NPIX + qrel + rp * 16 + n) * DHEAD + quad * 8);

  f32x4 O[RP][2], Ol[RP];
#pragma unroll
  for (int rp = 0; rp < RP; ++rp) {
    O[rp][0] = (f32x4){0.f, 0.f, 0.f, 0.f};
    O[rp][1] = (f32x4){0.f, 0.f, 0.f, 0.f};
    Ol[rp]   = (f32x4){0.f, 0.f, 0.f, 0.f};
  }
  const bf16_t one = (bf16_t)1.0f;
  const bf16x8 ones = {one, one, one, one, one, one, one, one};

  // permuted K row: pi(n) = (n>>2)*8 + (n&3); quad gives the d-offset
  const int pk = ((n >> 2) << 3) | (n & 3);
  const ushort* kb0 = kg + (size_t)(js * 1024 + pk) * DHEAD + quad * 8;
  const ushort* vb0 = vg + (size_t)n * NPIX + js * 1024 + quad * 8;

  bf16x8 kA[4], vA[4], kB[4], vB[4];
  ft_load(kb0, vb0, 0, kA, vA);
#pragma unroll 1
  for (int t = 0; t < 16; t += 2) {
    ft_load(kb0, vb0, t + 1, kB, vB);
    ft_compute(qf, kA, vA, ones, O, Ol);
    if (t + 2 < 16) ft_load(kb0, vb0, t + 2, kA, vA);
    ft_compute(qf, kB, vB, ones, O, Ol);
  }

  float* pb = part + ((size_t)js * 65536 + (size_t)bh * NPIX + qrel) * 36;
#pragma unroll
  for (int rp = 0; rp < RP; ++rp)
#pragma unroll
    for (int r = 0; r < 4; ++r) {
      const int q = rp * 16 + quad * 4 + r;
      pb[(size_t)q * 36 + n]      = O[rp][0][r];
      pb[(size_t)q * 36 + 16 + n] = O[rp][1][r];
      if (n == 0) pb[(size_t)q * 36 + 32] = Ol[rp][r];
    }
}

// ---------------------------------------------------------------------------
// out_fused r14: as r13 (1024 blocks of 16-px tiles) but loads raw f32
// wout fragments in-kernel (prep_swz eliminated).
// ---------------------------------------------------------------------------
__global__ void __launch_bounds__(256) out_fused(
    const float* __restrict__ part, const float* __restrict__ wout,
    const float* __restrict__ bias, float* __restrict__ out) {
  __shared__ ushort AOls[16 * 136];
  const int blk = blockIdx.x, tid = threadIdx.x;
  const int wave = tid >> 6, lane = tid & 63;
  const int n = lane & 15, quad = lane >> 4;
  const int bb = blk >> 8;
  const int p0 = (blk & 255) * 16;
  const int oc0 = wave * 32;

  bf16x8 wf[2][4];
#pragma unroll
  for (int mt = 0; mt < 2; ++mt)
#pragma unroll
    for (int k = 0; k < 4; ++k) {
      const float* ws = wout + (size_t)((wave * 2 + mt) * 16 + n) * CIN + k * 32 + quad * 8;
      float4 a = *(const float4*)ws;
      float4 b = *(const float4*)(ws + 4);
      wf[mt][k] = (bf16x8){(bf16_t)a.x, (bf16_t)a.y, (bf16_t)a.z, (bf16_t)a.w,
                           (bf16_t)b.x, (bf16_t)b.y, (bf16_t)b.z, (bf16_t)b.w};
    }

  // cooperative combine: thread = (px = tid>>4 0..15, c16 = tid&15 -> 8 ch)
  {
    const int px = tid >> 4, c16 = tid & 15;
    const int h = c16 >> 2, doff = (c16 & 3) * 8;
    const size_t rowbase = (size_t)(bb * NHEAD + h) * NPIX + p0 + px;
    float s[8];
#pragma unroll
    for (int e = 0; e < 8; ++e) s[e] = 0.f;
    float l = 0.f;
#pragma unroll
    for (int js = 0; js < 4; ++js) {
      const float* pp = part + ((size_t)js * 65536 + rowbase) * 36;
      f32x4 a0 = *(const f32x4*)(pp + doff);
      f32x4 a1 = *(const f32x4*)(pp + doff + 4);
#pragma unroll
      for (int e = 0; e < 4; ++e) {
        s[e]     += a0[e];
        s[4 + e] += a1[e];
      }
      l += pp[32];
    }
    const float inv = 1.f / l;
    bf16x8 o0;
#pragma unroll
    for (int e = 0; e < 8; ++e) o0[e] = (bf16_t)(s[e] * inv);
    *(bf16x8*)&AOls[px * 136 + c16 * 8] = o0;
  }
  __syncthreads();

  bf16x8 bfr[4];                       // [k] from LDS
#pragma unroll
  for (int k = 0; k < 4; ++k)
    bfr[k] = *(const bf16x8*)&AOls[n * 136 + k * 32 + quad * 8];

  f32x4 acc[2];
#pragma unroll
  for (int mt = 0; mt < 2; ++mt) acc[mt] = (f32x4){0.f, 0.f, 0.f, 0.f};
#pragma unroll
  for (int k = 0; k < 4; ++k)
#pragma unroll
    for (int mt = 0; mt < 2; ++mt)
      acc[mt] = __builtin_amdgcn_mfma_f32_16x16x32_bf16(
          wf[mt][k], bfr[k], acc[mt], 0, 0, 0);

#pragma unroll
  for (int mt = 0; mt < 2; ++mt) {
    const int oc = oc0 + mt * 16 + quad * 4;
#pragma unroll
    for (int r = 0; r < 4; ++r)
      out[((size_t)bb * CIN + oc + r) * NPIX + p0 + n] =
          acc[mt][r] + bias[oc + r];
  }
}

// ---------------------------------------------------------------------------
extern "C" void kernel_launch(void* const* d_in, const int* in_sizes, int n_in,
                              void* d_out, int out_size, void* d_ws, size_t ws_size,
                              hipStream_t stream) {
  const float* x     = (const float*)d_in[0];   // [4,128,64,64]
  const float* w_qkv = (const float*)d_in[1];   // [384,128]
  const float* w_out = (const float*)d_in[2];   // [128,128]
  const float* b_out = (const float*)d_in[3];   // [128]
  float* out = (float*)d_out;                   // [4,128,64,64]

  // ws (bytes): qb 0 | kb 4M | vT 8M | part 12M .. 12M+37.75M (~50 MB)
  char* base = (char*)d_ws;
  ushort* qb   = (ushort*)base;
  ushort* kb   = (ushort*)(base + (size_t)4 * 1024 * 1024);
  ushort* vT   = (ushort*)(base + (size_t)8 * 1024 * 1024);
  float*  part = (float*)(base + (size_t)12 * 1024 * 1024);

  qkv_mfma<<<dim3(512, 2), 256, 0, stream>>>(x, w_qkv, qb, kb, vT);
  flash_mfma<<<dim3(1024), 256, 0, stream>>>(qb, kb, vT, part);
  out_fused<<<dim3(1024), 256, 0, stream>>>(part, w_out, b_out, out);
}

// Round 5
// 145.389 us; speedup vs baseline: 1.5767x; 1.5767x over previous
//
#include <hip/hip_runtime.h>
#include <math.h>

#define NHEAD 4
#define DHEAD 32
#define NPIX  4096
#define CIN   128
#define RP    4   // query row-tiles per wave (64 queries)

typedef __bf16 bf16_t;
typedef __bf16 bf16x8 __attribute__((ext_vector_type(8)));
typedef __bf16 bf16x4 __attribute__((ext_vector_type(4)));
typedef float  f32x4  __attribute__((ext_vector_type(4)));

// 1/sqrt(32) * log2(e): folded into q weights so softmax exp is bare exp2.
constexpr float QSCALE = 0.17677669529663687f * 1.4426950408889634f;

// ---------------------------------------------------------------------------
// QKV projection.  [r14 verbatim — prep_swz folded in, grid (512,2)]
// ---------------------------------------------------------------------------
__global__ void __launch_bounds__(256) qkv_mfma(
    const float* __restrict__ x, const float* __restrict__ wqkv,
    ushort* __restrict__ qb, ushort* __restrict__ kb, ushort* __restrict__ vT) {
  __shared__ ushort Xls[32 * 136];
  const int blk = blockIdx.x, tid = threadIdx.x;
  const int half = blockIdx.y;
  const int wave = tid >> 6, lane = tid & 63;
  const int n = lane & 15, quad = lane >> 4;
  const int bb = blk >> 7;             // batch
  const int p0 = (blk & 127) * 32;     // 32-px tile

  {  // stage x[bb][c][p0..p0+31] -> Xls[p][c] bf16 (4x4 transpose)
    const int pc = tid & 7, c0 = (tid >> 3) * 4;
    const float* xp = x + ((size_t)bb * CIN + c0) * NPIX + p0 + pc * 4;
    float4 r0 = *(const float4*)xp;
    float4 r1 = *(const float4*)(xp + NPIX);
    float4 r2 = *(const float4*)(xp + 2 * NPIX);
    float4 r3 = *(const float4*)(xp + 3 * NPIX);
    bf16x4 w0 = {(bf16_t)r0.x, (bf16_t)r1.x, (bf16_t)r2.x, (bf16_t)r3.x};
    bf16x4 w1 = {(bf16_t)r0.y, (bf16_t)r1.y, (bf16_t)r2.y, (bf16_t)r3.y};
    bf16x4 w2 = {(bf16_t)r0.z, (bf16_t)r1.z, (bf16_t)r2.z, (bf16_t)r3.z};
    bf16x4 w3 = {(bf16_t)r0.w, (bf16_t)r1.w, (bf16_t)r2.w, (bf16_t)r3.w};
    *(bf16x4*)&Xls[(pc * 4 + 0) * 136 + c0] = w0;
    *(bf16x4*)&Xls[(pc * 4 + 1) * 136 + c0] = w1;
    *(bf16x4*)&Xls[(pc * 4 + 2) * 136 + c0] = w2;
    *(bf16x4*)&Xls[(pc * 4 + 3) * 136 + c0] = w3;
  }
  __syncthreads();

  bf16x8 xf[2][4];                     // [px-tile nt][k]
#pragma unroll
  for (int nt = 0; nt < 2; ++nt)
#pragma unroll
    for (int k = 0; k < 4; ++k)
      xf[nt][k] = *(const bf16x8*)&Xls[(nt * 16 + n) * 136 + k * 32 + quad * 8];

#pragma unroll
  for (int mt = 0; mt < 3; ++mt) {     // wave covers 48 oc = 3 tiles
    const int ot = half * 12 + wave * 3 + mt;   // 0..23
    const int type = ot >> 3;          // 0=q 1=k 2=v
    const int wt = ot & 7, head = wt >> 1, d0 = (wt & 1) * 16;
    const int bh = bb * NHEAD + head;
    const float sc = (type == 0) ? QSCALE : 1.f;
    bf16x8 wf4[4];
#pragma unroll
    for (int k = 0; k < 4; ++k) {
      const float* ws = wqkv + (size_t)(ot * 16 + n) * CIN + k * 32 + quad * 8;
      float4 a = *(const float4*)ws;
      float4 b = *(const float4*)(ws + 4);
      wf4[k] = (bf16x8){(bf16_t)(a.x * sc), (bf16_t)(a.y * sc),
                        (bf16_t)(a.z * sc), (bf16_t)(a.w * sc),
                        (bf16_t)(b.x * sc), (bf16_t)(b.y * sc),
                        (bf16_t)(b.z * sc), (bf16_t)(b.w * sc)};
    }
    f32x4 acc[2] = {{0.f, 0.f, 0.f, 0.f}, {0.f, 0.f, 0.f, 0.f}};
    if (type < 2) {
#pragma unroll
      for (int k = 0; k < 4; ++k)
#pragma unroll
        for (int nt = 0; nt < 2; ++nt)
          acc[nt] = __builtin_amdgcn_mfma_f32_16x16x32_bf16(wf4[k], xf[nt][k], acc[nt], 0, 0, 0);
      ushort* dst = (type == 0) ? qb : kb;
#pragma unroll
      for (int nt = 0; nt < 2; ++nt) {  // C[m=oc][n=px] -> [p][d] b64
        bf16x4 o = {(bf16_t)acc[nt][0], (bf16_t)acc[nt][1],
                    (bf16_t)acc[nt][2], (bf16_t)acc[nt][3]};
        *(bf16x4*)(dst + ((size_t)bh * NPIX + p0 + nt * 16 + n) * DHEAD + d0 + quad * 4) = o;
      }
    } else {
#pragma unroll
      for (int k = 0; k < 4; ++k)
#pragma unroll
        for (int nt = 0; nt < 2; ++nt)
          acc[nt] = __builtin_amdgcn_mfma_f32_16x16x32_bf16(xf[nt][k], wf4[k], acc[nt], 0, 0, 0);
#pragma unroll
      for (int nt = 0; nt < 2; ++nt) {  // C[m=px][n=d] -> vT[d][p] b64
        bf16x4 o = {(bf16_t)acc[nt][0], (bf16_t)acc[nt][1],
                    (bf16_t)acc[nt][2], (bf16_t)acc[nt][3]};
        *(bf16x4*)(vT + ((size_t)bh * DHEAD + d0 + n) * NPIX + p0 + nt * 16 + quad * 4) = o;
      }
    }
  }
}

// ---------------------------------------------------------------------------
// Flash attention.  r15: the r4 hypothesis WITHOUT the spill.  r4 forced
// __launch_bounds__(256,4) -> allocator capped at 64 VGPR -> the 32-reg K/V
// double-buffer spilled to scratch (FETCH 212 MB, WRITE 437 MB, 154 us).
// Now launch_bounds(256,2) (256-reg ceiling): RP=4 state is ~90-110 VGPR,
// so HW fits 4 waves/SIMD naturally, and the 1024-block grid supplies them.
// Keeps: XCD swizzle (r2: K/V L2-resident), setprio (r3: -3.6%), full
// 64-key double-buffered prefetch window.
// ---------------------------------------------------------------------------
__device__ __forceinline__ void ft_load(const ushort* kb0, const ushort* vb0,
                                        int t, bf16x8* kf, bf16x8* vf) {
#pragma unroll
  for (int p = 0; p < 2; ++p) {
#pragma unroll
    for (int s = 0; s < 2; ++s)
      kf[p * 2 + s] = *(const bf16x8*)(kb0 + (size_t)(t * 64 + p * 32 + s * 4) * DHEAD);
#pragma unroll
    for (int dp = 0; dp < 2; ++dp)
      vf[p * 2 + dp] = *(const bf16x8*)(vb0 + (size_t)dp * 16 * NPIX + t * 64 + p * 32);
  }
}

__device__ __forceinline__ void ft_compute(const bf16x8* qf, const bf16x8* kf,
                                           const bf16x8* vf, const bf16x8 ones,
                                           f32x4 O[RP][2], f32x4* Ol) {
  const f32x4 zero = {0.f, 0.f, 0.f, 0.f};
  __builtin_amdgcn_s_setprio(1);
#pragma unroll
  for (int p = 0; p < 2; ++p) {
#pragma unroll
    for (int rp = 0; rp < RP; ++rp) {
      f32x4 sa = __builtin_amdgcn_mfma_f32_16x16x32_bf16(kf[p * 2 + 0], qf[rp], zero, 0, 0, 0);
      f32x4 sb = __builtin_amdgcn_mfma_f32_16x16x32_bf16(kf[p * 2 + 1], qf[rp], zero, 0, 0, 0);
      bf16x8 pf;
#pragma unroll
      for (int r = 0; r < 4; ++r) {
        pf[r]     = (bf16_t)__builtin_amdgcn_exp2f(sa[r]);
        pf[r + 4] = (bf16_t)__builtin_amdgcn_exp2f(sb[r]);
      }
      O[rp][0] = __builtin_amdgcn_mfma_f32_16x16x32_bf16(pf, vf[p * 2 + 0], O[rp][0], 0, 0, 0);
      O[rp][1] = __builtin_amdgcn_mfma_f32_16x16x32_bf16(pf, vf[p * 2 + 1], O[rp][1], 0, 0, 0);
      Ol[rp]   = __builtin_amdgcn_mfma_f32_16x16x32_bf16(pf, ones, Ol[rp], 0, 0, 0);
    }
  }
  __builtin_amdgcn_s_setprio(0);
}

__global__ void __launch_bounds__(256, 2) flash_mfma(
    const ushort* __restrict__ qb, const ushort* __restrict__ kbuf,
    const ushort* __restrict__ vTb, float* __restrict__ part) {
  const int tid = threadIdx.x, wave = tid >> 6, lane = tid & 63;
  const int n = lane & 15, quad = lane >> 4;

  // XCD swizzle: group g = (js,bh); its 16 q-blocks all share id%8.
  // id = (g>>3)<<7 | qbk<<3 | (g&7) — bijective over 1024.
  const int id = blockIdx.x;
  const int g  = (id & 7) | ((id >> 7) << 3);   // 0..63
  const int qbk = (id >> 3) & 15;               // 0..15
  const int bh = g >> 2;                        // 0..15
  const int js = g & 3;                         // 0..3
  const int qrel = qbk * 256 + wave * 64;

  const ushort* kg = kbuf + (size_t)bh * NPIX * DHEAD;
  const ushort* vg = vTb + (size_t)bh * DHEAD * NPIX;

  bf16x8 qf[RP];
#pragma unroll
  for (int rp = 0; rp < RP; ++rp)
    qf[rp] = *(const bf16x8*)(qb +
        ((size_t)bh * NPIX + qrel + rp * 16 + n) * DHEAD + quad * 8);

  f32x4 O[RP][2], Ol[RP];
#pragma unroll
  for (int rp = 0; rp < RP; ++rp) {
    O[rp][0] = (f32x4){0.f, 0.f, 0.f, 0.f};
    O[rp][1] = (f32x4){0.f, 0.f, 0.f, 0.f};
    Ol[rp]   = (f32x4){0.f, 0.f, 0.f, 0.f};
  }
  const bf16_t one = (bf16_t)1.0f;
  const bf16x8 ones = {one, one, one, one, one, one, one, one};

  // permuted K row: pi(n) = (n>>2)*8 + (n&3); quad gives the d-offset
  const int pk = ((n >> 2) << 3) | (n & 3);
  const ushort* kb0 = kg + (size_t)(js * 1024 + pk) * DHEAD + quad * 8;
  const ushort* vb0 = vg + (size_t)n * NPIX + js * 1024 + quad * 8;

  bf16x8 kA[4], vA[4], kB[4], vB[4];
  ft_load(kb0, vb0, 0, kA, vA);
#pragma unroll 1
  for (int t = 0; t < 16; t += 2) {
    ft_load(kb0, vb0, t + 1, kB, vB);
    ft_compute(qf, kA, vA, ones, O, Ol);
    if (t + 2 < 16) ft_load(kb0, vb0, t + 2, kA, vA);
    ft_compute(qf, kB, vB, ones, O, Ol);
  }

  float* pb = part + ((size_t)js * 65536 + (size_t)bh * NPIX + qrel) * 36;
#pragma unroll
  for (int rp = 0; rp < RP; ++rp)
#pragma unroll
    for (int r = 0; r < 4; ++r) {
      const int q = rp * 16 + quad * 4 + r;
      pb[(size_t)q * 36 + n]      = O[rp][0][r];
      pb[(size_t)q * 36 + 16 + n] = O[rp][1][r];
      if (n == 0) pb[(size_t)q * 36 + 32] = Ol[rp][r];
    }
}

// ---------------------------------------------------------------------------
// out_fused.  [r14 verbatim — 1024 blocks of 16-px tiles, raw f32 wout]
// ---------------------------------------------------------------------------
__global__ void __launch_bounds__(256) out_fused(
    const float* __restrict__ part, const float* __restrict__ wout,
    const float* __restrict__ bias, float* __restrict__ out) {
  __shared__ ushort AOls[16 * 136];
  const int blk = blockIdx.x, tid = threadIdx.x;
  const int wave = tid >> 6, lane = tid & 63;
  const int n = lane & 15, quad = lane >> 4;
  const int bb = blk >> 8;
  const int p0 = (blk & 255) * 16;
  const int oc0 = wave * 32;

  bf16x8 wf[2][4];
#pragma unroll
  for (int mt = 0; mt < 2; ++mt)
#pragma unroll
    for (int k = 0; k < 4; ++k) {
      const float* ws = wout + (size_t)((wave * 2 + mt) * 16 + n) * CIN + k * 32 + quad * 8;
      float4 a = *(const float4*)ws;
      float4 b = *(const float4*)(ws + 4);
      wf[mt][k] = (bf16x8){(bf16_t)a.x, (bf16_t)a.y, (bf16_t)a.z, (bf16_t)a.w,
                           (bf16_t)b.x, (bf16_t)b.y, (bf16_t)b.z, (bf16_t)b.w};
    }

  // cooperative combine: thread = (px = tid>>4 0..15, c16 = tid&15 -> 8 ch)
  {
    const int px = tid >> 4, c16 = tid & 15;
    const int h = c16 >> 2, doff = (c16 & 3) * 8;
    const size_t rowbase = (size_t)(bb * NHEAD + h) * NPIX + p0 + px;
    float s[8];
#pragma unroll
    for (int e = 0; e < 8; ++e) s[e] = 0.f;
    float l = 0.f;
#pragma unroll
    for (int js = 0; js < 4; ++js) {
      const float* pp = part + ((size_t)js * 65536 + rowbase) * 36;
      f32x4 a0 = *(const f32x4*)(pp + doff);
      f32x4 a1 = *(const f32x4*)(pp + doff + 4);
#pragma unroll
      for (int e = 0; e < 4; ++e) {
        s[e]     += a0[e];
        s[4 + e] += a1[e];
      }
      l += pp[32];
    }
    const float inv = 1.f / l;
    bf16x8 o0;
#pragma unroll
    for (int e = 0; e < 8; ++e) o0[e] = (bf16_t)(s[e] * inv);
    *(bf16x8*)&AOls[px * 136 + c16 * 8] = o0;
  }
  __syncthreads();

  bf16x8 bfr[4];                       // [k] from LDS
#pragma unroll
  for (int k = 0; k < 4; ++k)
    bfr[k] = *(const bf16x8*)&AOls[n * 136 + k * 32 + quad * 8];

  f32x4 acc[2];
#pragma unroll
  for (int mt = 0; mt < 2; ++mt) acc[mt] = (f32x4){0.f, 0.f, 0.f, 0.f};
#pragma unroll
  for (int k = 0; k < 4; ++k)
#pragma unroll
    for (int mt = 0; mt < 2; ++mt)
      acc[mt] = __builtin_amdgcn_mfma_f32_16x16x32_bf16(
          wf[mt][k], bfr[k], acc[mt], 0, 0, 0);

#pragma unroll
  for (int mt = 0; mt < 2; ++mt) {
    const int oc = oc0 + mt * 16 + quad * 4;
#pragma unroll
    for (int r = 0; r < 4; ++r)
      out[((size_t)bb * CIN + oc + r) * NPIX + p0 + n] =
          acc[mt][r] + bias[oc + r];
  }
}

// ---------------------------------------------------------------------------
extern "C" void kernel_launch(void* const* d_in, const int* in_sizes, int n_in,
                              void* d_out, int out_size, void* d_ws, size_t ws_size,
                              hipStream_t stream) {
  const float* x     = (const float*)d_in[0];   // [4,128,64,64]
  const float* w_qkv = (const float*)d_in[1];   // [384,128]
  const float* w_out = (const float*)d_in[2];   // [128,128]
  const float* b_out = (const float*)d_in[3];   // [128]
  float* out = (float*)d_out;                   // [4,128,64,64]

  // ws (bytes): qb 0 | kb 4M | vT 8M | part 12M .. 12M+37.75M (~50 MB)
  char* base = (char*)d_ws;
  ushort* qb   = (ushort*)base;
  ushort* kb   = (ushort*)(base + (size_t)4 * 1024 * 1024);
  ushort* vT   = (ushort*)(base + (size_t)8 * 1024 * 1024);
  float*  part = (float*)(base + (size_t)12 * 1024 * 1024);

  qkv_mfma<<<dim3(512, 2), 256, 0, stream>>>(x, w_qkv, qb, kb, vT);
  flash_mfma<<<dim3(1024), 256, 0, stream>>>(qb, kb, vT, part);
  out_fused<<<dim3(1024), 256, 0, stream>>>(part, w_out, b_out, out);
}

// Round 6
// 142.433 us; speedup vs baseline: 1.6094x; 1.0208x over previous
//
#include <hip/hip_runtime.h>
#include <math.h>

#define NHEAD 4
#define DHEAD 32
#define NPIX  4096
#define CIN   128
#define RP    8   // query row-tiles per wave (128 queries) — proven optimum

typedef __bf16 bf16_t;
typedef __bf16 bf16x8 __attribute__((ext_vector_type(8)));
typedef __bf16 bf16x4 __attribute__((ext_vector_type(4)));
typedef float  f32x4  __attribute__((ext_vector_type(4)));

// 1/sqrt(32) * log2(e): folded into q weights so softmax exp is bare exp2.
constexpr float QSCALE = 0.17677669529663687f * 1.4426950408889634f;

// ---------------------------------------------------------------------------
// QKV projection.  [r14 verbatim — prep_swz folded in, grid (512,2)]
// ---------------------------------------------------------------------------
__global__ void __launch_bounds__(256) qkv_mfma(
    const float* __restrict__ x, const float* __restrict__ wqkv,
    ushort* __restrict__ qb, ushort* __restrict__ kb, ushort* __restrict__ vT) {
  __shared__ ushort Xls[32 * 136];
  const int blk = blockIdx.x, tid = threadIdx.x;
  const int half = blockIdx.y;
  const int wave = tid >> 6, lane = tid & 63;
  const int n = lane & 15, quad = lane >> 4;
  const int bb = blk >> 7;             // batch
  const int p0 = (blk & 127) * 32;     // 32-px tile

  {  // stage x[bb][c][p0..p0+31] -> Xls[p][c] bf16 (4x4 transpose)
    const int pc = tid & 7, c0 = (tid >> 3) * 4;
    const float* xp = x + ((size_t)bb * CIN + c0) * NPIX + p0 + pc * 4;
    float4 r0 = *(const float4*)xp;
    float4 r1 = *(const float4*)(xp + NPIX);
    float4 r2 = *(const float4*)(xp + 2 * NPIX);
    float4 r3 = *(const float4*)(xp + 3 * NPIX);
    bf16x4 w0 = {(bf16_t)r0.x, (bf16_t)r1.x, (bf16_t)r2.x, (bf16_t)r3.x};
    bf16x4 w1 = {(bf16_t)r0.y, (bf16_t)r1.y, (bf16_t)r2.y, (bf16_t)r3.y};
    bf16x4 w2 = {(bf16_t)r0.z, (bf16_t)r1.z, (bf16_t)r2.z, (bf16_t)r3.z};
    bf16x4 w3 = {(bf16_t)r0.w, (bf16_t)r1.w, (bf16_t)r2.w, (bf16_t)r3.w};
    *(bf16x4*)&Xls[(pc * 4 + 0) * 136 + c0] = w0;
    *(bf16x4*)&Xls[(pc * 4 + 1) * 136 + c0] = w1;
    *(bf16x4*)&Xls[(pc * 4 + 2) * 136 + c0] = w2;
    *(bf16x4*)&Xls[(pc * 4 + 3) * 136 + c0] = w3;
  }
  __syncthreads();

  bf16x8 xf[2][4];                     // [px-tile nt][k]
#pragma unroll
  for (int nt = 0; nt < 2; ++nt)
#pragma unroll
    for (int k = 0; k < 4; ++k)
      xf[nt][k] = *(const bf16x8*)&Xls[(nt * 16 + n) * 136 + k * 32 + quad * 8];

#pragma unroll
  for (int mt = 0; mt < 3; ++mt) {     // wave covers 48 oc = 3 tiles
    const int ot = half * 12 + wave * 3 + mt;   // 0..23
    const int type = ot >> 3;          // 0=q 1=k 2=v
    const int wt = ot & 7, head = wt >> 1, d0 = (wt & 1) * 16;
    const int bh = bb * NHEAD + head;
    const float sc = (type == 0) ? QSCALE : 1.f;
    bf16x8 wf4[4];
#pragma unroll
    for (int k = 0; k < 4; ++k) {
      const float* ws = wqkv + (size_t)(ot * 16 + n) * CIN + k * 32 + quad * 8;
      float4 a = *(const float4*)ws;
      float4 b = *(const float4*)(ws + 4);
      wf4[k] = (bf16x8){(bf16_t)(a.x * sc), (bf16_t)(a.y * sc),
                        (bf16_t)(a.z * sc), (bf16_t)(a.w * sc),
                        (bf16_t)(b.x * sc), (bf16_t)(b.y * sc),
                        (bf16_t)(b.z * sc), (bf16_t)(b.w * sc)};
    }
    f32x4 acc[2] = {{0.f, 0.f, 0.f, 0.f}, {0.f, 0.f, 0.f, 0.f}};
    if (type < 2) {
#pragma unroll
      for (int k = 0; k < 4; ++k)
#pragma unroll
        for (int nt = 0; nt < 2; ++nt)
          acc[nt] = __builtin_amdgcn_mfma_f32_16x16x32_bf16(wf4[k], xf[nt][k], acc[nt], 0, 0, 0);
      ushort* dst = (type == 0) ? qb : kb;
#pragma unroll
      for (int nt = 0; nt < 2; ++nt) {  // C[m=oc][n=px] -> [p][d] b64
        bf16x4 o = {(bf16_t)acc[nt][0], (bf16_t)acc[nt][1],
                    (bf16_t)acc[nt][2], (bf16_t)acc[nt][3]};
        *(bf16x4*)(dst + ((size_t)bh * NPIX + p0 + nt * 16 + n) * DHEAD + d0 + quad * 4) = o;
      }
    } else {
#pragma unroll
      for (int k = 0; k < 4; ++k)
#pragma unroll
        for (int nt = 0; nt < 2; ++nt)
          acc[nt] = __builtin_amdgcn_mfma_f32_16x16x32_bf16(xf[nt][k], wf4[k], acc[nt], 0, 0, 0);
#pragma unroll
      for (int nt = 0; nt < 2; ++nt) {  // C[m=px][n=d] -> vT[d][p] b64
        bf16x4 o = {(bf16_t)acc[nt][0], (bf16_t)acc[nt][1],
                    (bf16_t)acc[nt][2], (bf16_t)acc[nt][3]};
        *(bf16x4*)(vT + ((size_t)bh * DHEAD + d0 + n) * NPIX + p0 + nt * 16 + quad * 4) = o;
      }
    }
  }
}

// ---------------------------------------------------------------------------
// Flash attention.  r16: occupancy test with the per-wave load:compute
// ratio HELD CONSTANT.  r1/r5 both hit 63 us with RP=4 (same bytes, half
// compute per wave -> amortization loss, regardless of swizzle/window).
// Here RP stays 8 (proven 51 us structure, verbatim) and the KEY split
// doubles instead: JSC=8 -> each wave does 128 q x 512 keys (8 tiles),
// loads and compute halve together.  1024 blocks = 4 blocks/CU; VGPR=128
// (the (256,2) cap) fits exactly 4 waves/SIMD.  Cost: part doubles to
// 75.5 MB (guarded by ws_size; falls back to JSC=4 == r3).
// ---------------------------------------------------------------------------
__device__ __forceinline__ void ft_load(const ushort* kb0, const ushort* vb0,
                                        int t, bf16x8* kf, bf16x8* vf) {
#pragma unroll
  for (int p = 0; p < 2; ++p) {
#pragma unroll
    for (int s = 0; s < 2; ++s)
      kf[p * 2 + s] = *(const bf16x8*)(kb0 + (size_t)(t * 64 + p * 32 + s * 4) * DHEAD);
#pragma unroll
    for (int dp = 0; dp < 2; ++dp)
      vf[p * 2 + dp] = *(const bf16x8*)(vb0 + (size_t)dp * 16 * NPIX + t * 64 + p * 32);
  }
}

__device__ __forceinline__ void ft_compute(const bf16x8* qf, const bf16x8* kf,
                                           const bf16x8* vf, const bf16x8 ones,
                                           f32x4 O[RP][2], f32x4* Ol) {
  const f32x4 zero = {0.f, 0.f, 0.f, 0.f};
  __builtin_amdgcn_s_setprio(1);
#pragma unroll
  for (int p = 0; p < 2; ++p) {
#pragma unroll
    for (int rp = 0; rp < RP; ++rp) {
      f32x4 sa = __builtin_amdgcn_mfma_f32_16x16x32_bf16(kf[p * 2 + 0], qf[rp], zero, 0, 0, 0);
      f32x4 sb = __builtin_amdgcn_mfma_f32_16x16x32_bf16(kf[p * 2 + 1], qf[rp], zero, 0, 0, 0);
      bf16x8 pf;
#pragma unroll
      for (int r = 0; r < 4; ++r) {
        pf[r]     = (bf16_t)__builtin_amdgcn_exp2f(sa[r]);
        pf[r + 4] = (bf16_t)__builtin_amdgcn_exp2f(sb[r]);
      }
      O[rp][0] = __builtin_amdgcn_mfma_f32_16x16x32_bf16(pf, vf[p * 2 + 0], O[rp][0], 0, 0, 0);
      O[rp][1] = __builtin_amdgcn_mfma_f32_16x16x32_bf16(pf, vf[p * 2 + 1], O[rp][1], 0, 0, 0);
      Ol[rp]   = __builtin_amdgcn_mfma_f32_16x16x32_bf16(pf, ones, Ol[rp], 0, 0, 0);
    }
  }
  __builtin_amdgcn_s_setprio(0);
}

template <int JSC>
__global__ void __launch_bounds__(256, 2) flash_mfma(
    const ushort* __restrict__ qb, const ushort* __restrict__ kbuf,
    const ushort* __restrict__ vTb, float* __restrict__ part) {
  constexpr int KSL = NPIX / JSC;      // keys per js-slice
  constexpr int NT  = KSL / 64;        // 64-key tiles per wave
  const int tid = threadIdx.x, wave = tid >> 6, lane = tid & 63;
  const int n = lane & 15, quad = lane >> 4;

  // XCD swizzle: group g = (js,bh), 16*JSC groups; the 8 q-blocks of one
  // group share id%8 -> same XCD.  id = (g>>3)<<6 | qbk<<3 | (g&7).
  const int id = blockIdx.x;
  const int g  = (id & 7) | ((id >> 6) << 3);   // 0 .. 16*JSC-1
  const int qbk = (id >> 3) & 7;                // 0..7 (512 q each)
  const int bh = g / JSC;                       // 0..15
  const int js = g % JSC;                       // 0..JSC-1
  const int qrel = qbk * 512 + wave * 128;

  const ushort* kg = kbuf + (size_t)bh * NPIX * DHEAD;
  const ushort* vg = vTb + (size_t)bh * DHEAD * NPIX;

  bf16x8 qf[RP];
#pragma unroll
  for (int rp = 0; rp < RP; ++rp)
    qf[rp] = *(const bf16x8*)(qb +
        ((size_t)bh * NPIX + qrel + rp * 16 + n) * DHEAD + quad * 8);

  f32x4 O[RP][2], Ol[RP];
#pragma unroll
  for (int rp = 0; rp < RP; ++rp) {
    O[rp][0] = (f32x4){0.f, 0.f, 0.f, 0.f};
    O[rp][1] = (f32x4){0.f, 0.f, 0.f, 0.f};
    Ol[rp]   = (f32x4){0.f, 0.f, 0.f, 0.f};
  }
  const bf16_t one = (bf16_t)1.0f;
  const bf16x8 ones = {one, one, one, one, one, one, one, one};

  // permuted K row: pi(n) = (n>>2)*8 + (n&3); quad gives the d-offset
  const int pk = ((n >> 2) << 3) | (n & 3);
  const ushort* kb0 = kg + (size_t)(js * KSL + pk) * DHEAD + quad * 8;
  const ushort* vb0 = vg + (size_t)n * NPIX + js * KSL + quad * 8;

  bf16x8 kA[4], vA[4], kB[4], vB[4];
  ft_load(kb0, vb0, 0, kA, vA);
#pragma unroll 1
  for (int t = 0; t < NT; t += 2) {
    ft_load(kb0, vb0, t + 1, kB, vB);
    ft_compute(qf, kA, vA, ones, O, Ol);
    if (t + 2 < NT) ft_load(kb0, vb0, t + 2, kA, vA);
    ft_compute(qf, kB, vB, ones, O, Ol);
  }

  float* pb = part + ((size_t)js * 65536 + (size_t)bh * NPIX + qrel) * 36;
#pragma unroll
  for (int rp = 0; rp < RP; ++rp)
#pragma unroll
    for (int r = 0; r < 4; ++r) {
      const int q = rp * 16 + quad * 4 + r;
      pb[(size_t)q * 36 + n]      = O[rp][0][r];
      pb[(size_t)q * 36 + 16 + n] = O[rp][1][r];
      if (n == 0) pb[(size_t)q * 36 + 32] = Ol[rp][r];
    }
}

// ---------------------------------------------------------------------------
// out_fused r16: as r15 but the combine loop runs over a runtime jsc
// (4 or 8 key-splits).
// ---------------------------------------------------------------------------
__global__ void __launch_bounds__(256) out_fused(
    const float* __restrict__ part, const float* __restrict__ wout,
    const float* __restrict__ bias, float* __restrict__ out, int jsc) {
  __shared__ ushort AOls[16 * 136];
  const int blk = blockIdx.x, tid = threadIdx.x;
  const int wave = tid >> 6, lane = tid & 63;
  const int n = lane & 15, quad = lane >> 4;
  const int bb = blk >> 8;
  const int p0 = (blk & 255) * 16;
  const int oc0 = wave * 32;

  bf16x8 wf[2][4];
#pragma unroll
  for (int mt = 0; mt < 2; ++mt)
#pragma unroll
    for (int k = 0; k < 4; ++k) {
      const float* ws = wout + (size_t)((wave * 2 + mt) * 16 + n) * CIN + k * 32 + quad * 8;
      float4 a = *(const float4*)ws;
      float4 b = *(const float4*)(ws + 4);
      wf[mt][k] = (bf16x8){(bf16_t)a.x, (bf16_t)a.y, (bf16_t)a.z, (bf16_t)a.w,
                           (bf16_t)b.x, (bf16_t)b.y, (bf16_t)b.z, (bf16_t)b.w};
    }

  // cooperative combine: thread = (px = tid>>4 0..15, c16 = tid&15 -> 8 ch)
  {
    const int px = tid >> 4, c16 = tid & 15;
    const int h = c16 >> 2, doff = (c16 & 3) * 8;
    const size_t rowbase = (size_t)(bb * NHEAD + h) * NPIX + p0 + px;
    float s[8];
#pragma unroll
    for (int e = 0; e < 8; ++e) s[e] = 0.f;
    float l = 0.f;
#pragma unroll 4
    for (int js = 0; js < jsc; ++js) {
      const float* pp = part + ((size_t)js * 65536 + rowbase) * 36;
      f32x4 a0 = *(const f32x4*)(pp + doff);
      f32x4 a1 = *(const f32x4*)(pp + doff + 4);
#pragma unroll
      for (int e = 0; e < 4; ++e) {
        s[e]     += a0[e];
        s[4 + e] += a1[e];
      }
      l += pp[32];
    }
    const float inv = 1.f / l;
    bf16x8 o0;
#pragma unroll
    for (int e = 0; e < 8; ++e) o0[e] = (bf16_t)(s[e] * inv);
    *(bf16x8*)&AOls[px * 136 + c16 * 8] = o0;
  }
  __syncthreads();

  bf16x8 bfr[4];                       // [k] from LDS
#pragma unroll
  for (int k = 0; k < 4; ++k)
    bfr[k] = *(const bf16x8*)&AOls[n * 136 + k * 32 + quad * 8];

  f32x4 acc[2];
#pragma unroll
  for (int mt = 0; mt < 2; ++mt) acc[mt] = (f32x4){0.f, 0.f, 0.f, 0.f};
#pragma unroll
  for (int k = 0; k < 4; ++k)
#pragma unroll
    for (int mt = 0; mt < 2; ++mt)
      acc[mt] = __builtin_amdgcn_mfma_f32_16x16x32_bf16(
          wf[mt][k], bfr[k], acc[mt], 0, 0, 0);

#pragma unroll
  for (int mt = 0; mt < 2; ++mt) {
    const int oc = oc0 + mt * 16 + quad * 4;
#pragma unroll
    for (int r = 0; r < 4; ++r)
      out[((size_t)bb * CIN + oc + r) * NPIX + p0 + n] =
          acc[mt][r] + bias[oc + r];
  }
}

// ---------------------------------------------------------------------------
extern "C" void kernel_launch(void* const* d_in, const int* in_sizes, int n_in,
                              void* d_out, int out_size, void* d_ws, size_t ws_size,
                              hipStream_t stream) {
  const float* x     = (const float*)d_in[0];   // [4,128,64,64]
  const float* w_qkv = (const float*)d_in[1];   // [384,128]
  const float* w_out = (const float*)d_in[2];   // [128,128]
  const float* b_out = (const float*)d_in[3];   // [128]
  float* out = (float*)d_out;                   // [4,128,64,64]

  // ws (bytes): qb 0 | kb 4M | vT 8M | part 12M.. (JSC*65536*36*4 B)
  char* base = (char*)d_ws;
  ushort* qb   = (ushort*)base;
  ushort* kb   = (ushort*)(base + (size_t)4 * 1024 * 1024);
  ushort* vT   = (ushort*)(base + (size_t)8 * 1024 * 1024);
  float*  part = (float*)(base + (size_t)12 * 1024 * 1024);

  const size_t need8 = (size_t)12 * 1024 * 1024 +
                       (size_t)8 * 65536 * 36 * sizeof(float);
  const int jsc = (ws_size >= need8) ? 8 : 4;

  qkv_mfma<<<dim3(512, 2), 256, 0, stream>>>(x, w_qkv, qb, kb, vT);
  if (jsc == 8)
    flash_mfma<8><<<dim3(1024), 256, 0, stream>>>(qb, kb, vT, part);
  else
    flash_mfma<4><<<dim3(512), 256, 0, stream>>>(qb, kb, vT, part);
  out_fused<<<dim3(1024), 256, 0, stream>>>(part, w_out, b_out, out, jsc);
}

// Round 7
// 131.213 us; speedup vs baseline: 1.7470x; 1.0855x over previous
//
#include <hip/hip_runtime.h>
#include <math.h>

#define NHEAD 4
#define DHEAD 32
#define NPIX  4096
#define CIN   128
#define RP    8   // query row-tiles per wave (128 queries) — proven optimum

typedef __bf16 bf16_t;
typedef __bf16 bf16x8 __attribute__((ext_vector_type(8)));
typedef __bf16 bf16x4 __attribute__((ext_vector_type(4)));
typedef float  f32x4  __attribute__((ext_vector_type(4)));

// 1/sqrt(32) * log2(e): folded into q weights so softmax exp is bare exp2.
constexpr float QSCALE = 0.17677669529663687f * 1.4426950408889634f;

// ---------------------------------------------------------------------------
// QKV projection.  [r14 verbatim — prep_swz folded in, grid (512,2)]
// ---------------------------------------------------------------------------
__global__ void __launch_bounds__(256) qkv_mfma(
    const float* __restrict__ x, const float* __restrict__ wqkv,
    ushort* __restrict__ qb, ushort* __restrict__ kb, ushort* __restrict__ vT) {
  __shared__ ushort Xls[32 * 136];
  const int blk = blockIdx.x, tid = threadIdx.x;
  const int half = blockIdx.y;
  const int wave = tid >> 6, lane = tid & 63;
  const int n = lane & 15, quad = lane >> 4;
  const int bb = blk >> 7;             // batch
  const int p0 = (blk & 127) * 32;     // 32-px tile

  {  // stage x[bb][c][p0..p0+31] -> Xls[p][c] bf16 (4x4 transpose)
    const int pc = tid & 7, c0 = (tid >> 3) * 4;
    const float* xp = x + ((size_t)bb * CIN + c0) * NPIX + p0 + pc * 4;
    float4 r0 = *(const float4*)xp;
    float4 r1 = *(const float4*)(xp + NPIX);
    float4 r2 = *(const float4*)(xp + 2 * NPIX);
    float4 r3 = *(const float4*)(xp + 3 * NPIX);
    bf16x4 w0 = {(bf16_t)r0.x, (bf16_t)r1.x, (bf16_t)r2.x, (bf16_t)r3.x};
    bf16x4 w1 = {(bf16_t)r0.y, (bf16_t)r1.y, (bf16_t)r2.y, (bf16_t)r3.y};
    bf16x4 w2 = {(bf16_t)r0.z, (bf16_t)r1.z, (bf16_t)r2.z, (bf16_t)r3.z};
    bf16x4 w3 = {(bf16_t)r0.w, (bf16_t)r1.w, (bf16_t)r2.w, (bf16_t)r3.w};
    *(bf16x4*)&Xls[(pc * 4 + 0) * 136 + c0] = w0;
    *(bf16x4*)&Xls[(pc * 4 + 1) * 136 + c0] = w1;
    *(bf16x4*)&Xls[(pc * 4 + 2) * 136 + c0] = w2;
    *(bf16x4*)&Xls[(pc * 4 + 3) * 136 + c0] = w3;
  }
  __syncthreads();

  bf16x8 xf[2][4];                     // [px-tile nt][k]
#pragma unroll
  for (int nt = 0; nt < 2; ++nt)
#pragma unroll
    for (int k = 0; k < 4; ++k)
      xf[nt][k] = *(const bf16x8*)&Xls[(nt * 16 + n) * 136 + k * 32 + quad * 8];

#pragma unroll
  for (int mt = 0; mt < 3; ++mt) {     // wave covers 48 oc = 3 tiles
    const int ot = half * 12 + wave * 3 + mt;   // 0..23
    const int type = ot >> 3;          // 0=q 1=k 2=v
    const int wt = ot & 7, head = wt >> 1, d0 = (wt & 1) * 16;
    const int bh = bb * NHEAD + head;
    const float sc = (type == 0) ? QSCALE : 1.f;
    bf16x8 wf4[4];
#pragma unroll
    for (int k = 0; k < 4; ++k) {
      const float* ws = wqkv + (size_t)(ot * 16 + n) * CIN + k * 32 + quad * 8;
      float4 a = *(const float4*)ws;
      float4 b = *(const float4*)(ws + 4);
      wf4[k] = (bf16x8){(bf16_t)(a.x * sc), (bf16_t)(a.y * sc),
                        (bf16_t)(a.z * sc), (bf16_t)(a.w * sc),
                        (bf16_t)(b.x * sc), (bf16_t)(b.y * sc),
                        (bf16_t)(b.z * sc), (bf16_t)(b.w * sc)};
    }
    f32x4 acc[2] = {{0.f, 0.f, 0.f, 0.f}, {0.f, 0.f, 0.f, 0.f}};
    if (type < 2) {
#pragma unroll
      for (int k = 0; k < 4; ++k)
#pragma unroll
        for (int nt = 0; nt < 2; ++nt)
          acc[nt] = __builtin_amdgcn_mfma_f32_16x16x32_bf16(wf4[k], xf[nt][k], acc[nt], 0, 0, 0);
      ushort* dst = (type == 0) ? qb : kb;
#pragma unroll
      for (int nt = 0; nt < 2; ++nt) {  // C[m=oc][n=px] -> [p][d] b64
        bf16x4 o = {(bf16_t)acc[nt][0], (bf16_t)acc[nt][1],
                    (bf16_t)acc[nt][2], (bf16_t)acc[nt][3]};
        *(bf16x4*)(dst + ((size_t)bh * NPIX + p0 + nt * 16 + n) * DHEAD + d0 + quad * 4) = o;
      }
    } else {
#pragma unroll
      for (int k = 0; k < 4; ++k)
#pragma unroll
        for (int nt = 0; nt < 2; ++nt)
          acc[nt] = __builtin_amdgcn_mfma_f32_16x16x32_bf16(xf[nt][k], wf4[k], acc[nt], 0, 0, 0);
#pragma unroll
      for (int nt = 0; nt < 2; ++nt) {  // C[m=px][n=d] -> vT[d][p] b64
        bf16x4 o = {(bf16_t)acc[nt][0], (bf16_t)acc[nt][1],
                    (bf16_t)acc[nt][2], (bf16_t)acc[nt][3]};
        *(bf16x4*)(vT + ((size_t)bh * DHEAD + d0 + n) * NPIX + p0 + nt * 16 + quad * 4) = o;
      }
    }
  }
}

// ---------------------------------------------------------------------------
// Flash attention.  r17: intra-block key-split.  Block = (bh, 128-query
// tile); wave = one 1024-key quarter (js = wave) — the per-wave inner loop
// is r3's proven 51-us core VERBATIM (128 q x 1024 keys, NT=16, setprio,
// reg double-buffer).  Epilogue: O/l partials -> LDS (73.7 KB, stride-36
// f32, same layout as the old global 'part'), barrier, 256-thread combine
// + normalize + bf16 cast, write final ao (4 MB) — replacing the 37.75 MB
// f32 part write + 37.75 MB read in out_fused.  512 blocks; natural
// id%8 == bh%8 keeps each bh's K/V on one XCD (hot set 2 x 512 KB per L2).
// ---------------------------------------------------------------------------
__device__ __forceinline__ void ft_load(const ushort* kb0, const ushort* vb0,
                                        int t, bf16x8* kf, bf16x8* vf) {
#pragma unroll
  for (int p = 0; p < 2; ++p) {
#pragma unroll
    for (int s = 0; s < 2; ++s)
      kf[p * 2 + s] = *(const bf16x8*)(kb0 + (size_t)(t * 64 + p * 32 + s * 4) * DHEAD);
#pragma unroll
    for (int dp = 0; dp < 2; ++dp)
      vf[p * 2 + dp] = *(const bf16x8*)(vb0 + (size_t)dp * 16 * NPIX + t * 64 + p * 32);
  }
}

__device__ __forceinline__ void ft_compute(const bf16x8* qf, const bf16x8* kf,
                                           const bf16x8* vf, const bf16x8 ones,
                                           f32x4 O[RP][2], f32x4* Ol) {
  const f32x4 zero = {0.f, 0.f, 0.f, 0.f};
  __builtin_amdgcn_s_setprio(1);
#pragma unroll
  for (int p = 0; p < 2; ++p) {
#pragma unroll
    for (int rp = 0; rp < RP; ++rp) {
      f32x4 sa = __builtin_amdgcn_mfma_f32_16x16x32_bf16(kf[p * 2 + 0], qf[rp], zero, 0, 0, 0);
      f32x4 sb = __builtin_amdgcn_mfma_f32_16x16x32_bf16(kf[p * 2 + 1], qf[rp], zero, 0, 0, 0);
      bf16x8 pf;
#pragma unroll
      for (int r = 0; r < 4; ++r) {
        pf[r]     = (bf16_t)__builtin_amdgcn_exp2f(sa[r]);
        pf[r + 4] = (bf16_t)__builtin_amdgcn_exp2f(sb[r]);
      }
      O[rp][0] = __builtin_amdgcn_mfma_f32_16x16x32_bf16(pf, vf[p * 2 + 0], O[rp][0], 0, 0, 0);
      O[rp][1] = __builtin_amdgcn_mfma_f32_16x16x32_bf16(pf, vf[p * 2 + 1], O[rp][1], 0, 0, 0);
      Ol[rp]   = __builtin_amdgcn_mfma_f32_16x16x32_bf16(pf, ones, Ol[rp], 0, 0, 0);
    }
  }
  __builtin_amdgcn_s_setprio(0);
}

__global__ void __launch_bounds__(256, 2) flash_mfma(
    const ushort* __restrict__ qb, const ushort* __restrict__ kbuf,
    const ushort* __restrict__ vTb, ushort* __restrict__ ao) {
  __shared__ float Ols[4 * 128 * 36];   // [wave][q][d0..31, l@32] (73.7 KB)
  const int tid = threadIdx.x, wave = tid >> 6, lane = tid & 63;
  const int n = lane & 15, quad = lane >> 4;

  const int id = blockIdx.x;
  const int bh = id & 15;              // id%8 == bh%8 -> per-bh XCD affinity
  const int qblk = id >> 4;            // 0..31
  const int js = wave;                 // intra-block key split
  const int qrel = qblk * 128;

  const ushort* kg = kbuf + (size_t)bh * NPIX * DHEAD;
  const ushort* vg = vTb + (size_t)bh * DHEAD * NPIX;

  bf16x8 qf[RP];
#pragma unroll
  for (int rp = 0; rp < RP; ++rp)
    qf[rp] = *(const bf16x8*)(qb +
        ((size_t)bh * NPIX + qrel + rp * 16 + n) * DHEAD + quad * 8);

  f32x4 O[RP][2], Ol[RP];
#pragma unroll
  for (int rp = 0; rp < RP; ++rp) {
    O[rp][0] = (f32x4){0.f, 0.f, 0.f, 0.f};
    O[rp][1] = (f32x4){0.f, 0.f, 0.f, 0.f};
    Ol[rp]   = (f32x4){0.f, 0.f, 0.f, 0.f};
  }
  const bf16_t one = (bf16_t)1.0f;
  const bf16x8 ones = {one, one, one, one, one, one, one, one};

  // permuted K row: pi(n) = (n>>2)*8 + (n&3); quad gives the d-offset
  const int pk = ((n >> 2) << 3) | (n & 3);
  const ushort* kb0 = kg + (size_t)(js * 1024 + pk) * DHEAD + quad * 8;
  const ushort* vb0 = vg + (size_t)n * NPIX + js * 1024 + quad * 8;

  bf16x8 kA[4], vA[4], kB[4], vB[4];
  ft_load(kb0, vb0, 0, kA, vA);
#pragma unroll 1
  for (int t = 0; t < 16; t += 2) {
    ft_load(kb0, vb0, t + 1, kB, vB);
    ft_compute(qf, kA, vA, ones, O, Ol);
    if (t + 2 < 16) ft_load(kb0, vb0, t + 2, kA, vA);
    ft_compute(qf, kB, vB, ones, O, Ol);
  }

  // partials -> LDS (layout identical to old global 'part' rows)
  {
    float* pb = &Ols[wave * 128 * 36];
#pragma unroll
    for (int rp = 0; rp < RP; ++rp)
#pragma unroll
      for (int r = 0; r < 4; ++r) {
        const int q = rp * 16 + quad * 4 + r;
        pb[q * 36 + n]      = O[rp][0][r];
        pb[q * 36 + 16 + n] = O[rp][1][r];
        if (n == 0) pb[q * 36 + 32] = Ol[rp][r];
      }
  }
  __syncthreads();

  // combine 4 wave-partials, normalize, cast, store bf16 ao
  {
    const int q = tid >> 1, dh = tid & 1;
    f32x4 A0 = {0.f, 0.f, 0.f, 0.f}, A1 = A0, A2 = A0, A3 = A0;
    float l = 0.f;
#pragma unroll
    for (int w = 0; w < 4; ++w) {
      const float* pp = &Ols[(w * 128 + q) * 36 + dh * 16];
      A0 += *(const f32x4*)pp;
      A1 += *(const f32x4*)(pp + 4);
      A2 += *(const f32x4*)(pp + 8);
      A3 += *(const f32x4*)(pp + 12);
      l += pp[32 - dh * 16];
    }
    const float inv = 1.f / l;
    bf16x8 o0, o1;
#pragma unroll
    for (int e = 0; e < 4; ++e) {
      o0[e]     = (bf16_t)(A0[e] * inv);
      o0[e + 4] = (bf16_t)(A1[e] * inv);
      o1[e]     = (bf16_t)(A2[e] * inv);
      o1[e + 4] = (bf16_t)(A3[e] * inv);
    }
    ushort* dst = ao + ((size_t)((bh >> 2) * NPIX + qrel + q) * CIN
                        + (bh & 3) * 32 + dh * 16);
    *(bf16x8*)dst = o0;
    *(bf16x8*)(dst + 8) = o1;
  }
}

// ---------------------------------------------------------------------------
// out_fused r17: combine removed — reads final bf16 ao fragments directly
// (L2/L3-hot, 4 MB total), pure out-projection MFMA + bias.
// ---------------------------------------------------------------------------
__global__ void __launch_bounds__(256) out_fused(
    const ushort* __restrict__ ao, const float* __restrict__ wout,
    const float* __restrict__ bias, float* __restrict__ out) {
  const int blk = blockIdx.x, tid = threadIdx.x;
  const int wave = tid >> 6, lane = tid & 63;
  const int n = lane & 15, quad = lane >> 4;
  const int bb = blk >> 8;
  const int p0 = (blk & 255) * 16;
  const int oc0 = wave * 32;

  bf16x8 wf[2][4];
#pragma unroll
  for (int mt = 0; mt < 2; ++mt)
#pragma unroll
    for (int k = 0; k < 4; ++k) {
      const float* ws = wout + (size_t)((wave * 2 + mt) * 16 + n) * CIN + k * 32 + quad * 8;
      float4 a = *(const float4*)ws;
      float4 b = *(const float4*)(ws + 4);
      wf[mt][k] = (bf16x8){(bf16_t)a.x, (bf16_t)a.y, (bf16_t)a.z, (bf16_t)a.w,
                           (bf16_t)b.x, (bf16_t)b.y, (bf16_t)b.z, (bf16_t)b.w};
    }

  bf16x8 bfr[4];                       // [k] straight from global ao
#pragma unroll
  for (int k = 0; k < 4; ++k)
    bfr[k] = *(const bf16x8*)(ao +
        ((size_t)(bb * NPIX + p0 + n) * CIN + k * 32 + quad * 8));

  f32x4 acc[2];
#pragma unroll
  for (int mt = 0; mt < 2; ++mt) acc[mt] = (f32x4){0.f, 0.f, 0.f, 0.f};
#pragma unroll
  for (int k = 0; k < 4; ++k)
#pragma unroll
    for (int mt = 0; mt < 2; ++mt)
      acc[mt] = __builtin_amdgcn_mfma_f32_16x16x32_bf16(
          wf[mt][k], bfr[k], acc[mt], 0, 0, 0);

#pragma unroll
  for (int mt = 0; mt < 2; ++mt) {
    const int oc = oc0 + mt * 16 + quad * 4;
#pragma unroll
    for (int r = 0; r < 4; ++r)
      out[((size_t)bb * CIN + oc + r) * NPIX + p0 + n] =
          acc[mt][r] + bias[oc + r];
  }
}

// ---------------------------------------------------------------------------
extern "C" void kernel_launch(void* const* d_in, const int* in_sizes, int n_in,
                              void* d_out, int out_size, void* d_ws, size_t ws_size,
                              hipStream_t stream) {
  const float* x     = (const float*)d_in[0];   // [4,128,64,64]
  const float* w_qkv = (const float*)d_in[1];   // [384,128]
  const float* w_out = (const float*)d_in[2];   // [128,128]
  const float* b_out = (const float*)d_in[3];   // [128]
  float* out = (float*)d_out;                   // [4,128,64,64]

  // ws (bytes): qb 0 | kb 4M | vT 8M | ao 12M..16M  (16 MB total)
  char* base = (char*)d_ws;
  ushort* qb = (ushort*)base;
  ushort* kb = (ushort*)(base + (size_t)4 * 1024 * 1024);
  ushort* vT = (ushort*)(base + (size_t)8 * 1024 * 1024);
  ushort* ao = (ushort*)(base + (size_t)12 * 1024 * 1024);

  qkv_mfma<<<dim3(512, 2), 256, 0, stream>>>(x, w_qkv, qb, kb, vT);
  flash_mfma<<<dim3(512), 256, 0, stream>>>(qb, kb, vT, ao);
  out_fused<<<dim3(1024), 256, 0, stream>>>(ao, w_out, b_out, out);
}